// Round 7
// baseline (76.057 us; speedup 1.0000x reference)
//
#include <hip/hip_runtime.h>
#include <hip/hip_bf16.h>

#define B_ROWS 4096
#define D_DIM  256
#define TWO_B  8192
// reps row stride in bytes = 256 * 2 = 512

typedef float f32x4  __attribute__((ext_vector_type(4)));
typedef short bf16x8 __attribute__((ext_vector_type(8)));

#define CCHUNK      1024
#define TPS         4               // 16-col tiles per LDS stage
#define STAGE_BYTES (TPS * 8192)    // 32 KiB
#define NSTAGES     (CCHUNK / (TPS * 16))

#define SC2 1442.6951f   // 1000 * log2(e)
#define M0  1442.6951f   // anchor: logit2 of sim == 1 (the diagonal)

__device__ __forceinline__ void async_copy16(void* lds_dst, const void* gsrc) {
    __builtin_amdgcn_global_load_lds(
        (__attribute__((address_space(1))) void*)(gsrc),
        (__attribute__((address_space(3))) void*)(lds_dst), 16, 0, 0);
}

// ---------------- kernel 1: normalize rows, compute positives, emit bf16 reps
__global__ __launch_bounds__(256) void k_prep(const float* __restrict__ p1,
                                              const float* __restrict__ p2,
                                              __hip_bfloat16* __restrict__ reps,
                                              float* __restrict__ pos) {
    const int r = blockIdx.x;
    const int t = threadIdx.x;
    float e1 = p1[r * D_DIM + t];
    float e2 = p2[r * D_DIM + t];
    float s11 = e1 * e1, s22 = e2 * e2, s12 = e1 * e2;
    #pragma unroll
    for (int m = 1; m < 64; m <<= 1) {
        s11 += __shfl_xor(s11, m);
        s22 += __shfl_xor(s22, m);
        s12 += __shfl_xor(s12, m);
    }
    __shared__ float red[3][4];
    const int w = t >> 6, l = t & 63;
    if (l == 0) { red[0][w] = s11; red[1][w] = s22; red[2][w] = s12; }
    __syncthreads();
    s11 = red[0][0] + red[0][1] + red[0][2] + red[0][3];
    s22 = red[1][0] + red[1][1] + red[1][2] + red[1][3];
    s12 = red[2][0] + red[2][1] + red[2][2] + red[2][3];
    const float n1 = fmaxf(sqrtf(s11), 1e-12f);
    const float n2 = fmaxf(sqrtf(s22), 1e-12f);
    reps[r * D_DIM + t]            = __float2bfloat16(e1 / n1);
    reps[(B_ROWS + r) * D_DIM + t] = __float2bfloat16(e2 / n2);
    if (t == 0) pos[r] = s12 / (n1 * n2);
}

// ---------------- kernel 2: fused reps·repsT -> row-wise sum of 2^(1443*sim - M0)
// WG: 256 thr (4 waves). Each wave: 32 rows (2 M-tiles). WG: 128 rows x CCHUNK cols.
__global__ __launch_bounds__(256) void k_simlse(const __hip_bfloat16* __restrict__ reps,
                                                float* __restrict__ s_rows) {
    __shared__ char lds[STAGE_BYTES];
    const int t   = threadIdx.x;
    const int w   = t >> 6;
    const int l   = t & 63;
    const int c16 = l & 15;
    const int g   = l >> 4;     // 0..3

    const int row_base = blockIdx.x * 128 + w * 32;
    const int col_base = blockIdx.y * CCHUNK;
    const char* repsB = (const char*)reps;

    // A fragments in registers: 2 M-tiles x 8 k-steps, 16B per lane each
    bf16x8 afrag[2][8];
    #pragma unroll
    for (int mt = 0; mt < 2; ++mt) {
        const int arow = row_base + mt * 16 + c16;
        #pragma unroll
        for (int kk = 0; kk < 8; ++kk)
            afrag[mt][kk] = *(const bf16x8*)(repsB + arow * 512 + kk * 64 + g * 16);
    }

    float s[8];
    #pragma unroll
    for (int i = 0; i < 8; ++i) s[i] = 0.f;

    for (int st = 0; st < NSTAGES; ++st) {
        const int cstage = col_base + st * (TPS * 16);
        // stage TPS*16 cols x 256 k (bf16) into LDS in fragment order:
        // lds[tt*8192 + kk*1024 + g*256 + c*16] = reps[cstage+tt*16+c][k = kk*32+g*8 .. +8]
        #pragma unroll
        for (int i = 0; i < 8; ++i) {
            const int a  = i * 4096 + w * 1024 + l * 16;
            const int tt = a >> 13;
            const int rr = a & 8191;
            const int kk = rr >> 10;
            const int gg = (rr >> 8) & 3;
            const int cc = (rr >> 4) & 15;
            const int col = cstage + tt * 16 + cc;
            async_copy16(lds + i * 4096 + w * 1024,            // wave-uniform base; HW adds lane*16
                         repsB + col * 512 + kk * 64 + gg * 16);
        }
        __syncthreads();   // drains vmcnt -> LDS staged

        #pragma unroll
        for (int tt = 0; tt < TPS; ++tt) {
            f32x4 acc0 = {0.f, 0.f, 0.f, 0.f};
            f32x4 acc1 = {0.f, 0.f, 0.f, 0.f};
            #pragma unroll
            for (int kk = 0; kk < 8; ++kk) {
                const bf16x8 b = *(const bf16x8*)(lds + tt * 8192 + kk * 1024 + l * 16);
                acc0 = __builtin_amdgcn_mfma_f32_16x16x32_bf16(afrag[0][kk], b, acc0, 0, 0, 0);
                acc1 = __builtin_amdgcn_mfma_f32_16x16x32_bf16(afrag[1][kk], b, acc1, 0, 0, 0);
            }
            // D layout: row = g*4 + reg, col = c16  (verified m89/m91)
            const float tmax =
                fmaxf(fmaxf(fmaxf(acc0[0], acc0[1]), fmaxf(acc0[2], acc0[3])),
                      fmaxf(fmaxf(acc1[0], acc1[1]), fmaxf(acc1[2], acc1[3])));
            // only tiles containing a diagonal element matter; dropped terms < 2^-144
            if (__any(tmax > 0.90f)) {
                #pragma unroll
                for (int r = 0; r < 4; ++r) s[r]     += exp2f(acc0[r] * SC2 - M0);
                #pragma unroll
                for (int r = 0; r < 4; ++r) s[4 + r] += exp2f(acc1[r] * SC2 - M0);
            }
        }
        __syncthreads();   // all waves done reading before restage
    }

    // reduce s over the 16 lanes (cols) of each lane-group, then one atomic per row
    #pragma unroll
    for (int i = 0; i < 8; ++i) {
        #pragma unroll
        for (int m = 1; m < 16; m <<= 1) s[i] += __shfl_xor(s[i], m);
    }
    if (c16 == 0) {
        #pragma unroll
        for (int mt = 0; mt < 2; ++mt)
            #pragma unroll
            for (int r = 0; r < 4; ++r)
                atomicAdd(&s_rows[row_base + mt * 16 + g * 4 + r], s[mt * 4 + r]);
    }
}

// ---------------- kernel 3: finalize loss and sum(positives)
__global__ __launch_bounds__(256) void k_final(const float* __restrict__ s_rows,
                                               const float* __restrict__ pos,
                                               float* __restrict__ out) {
    const float LN2 = 0.69314718f;
    const int t = threadIdx.x;
    float lsum = 0.f;
    for (int r = t; r < TWO_B; r += 256) {
        const float lse = LN2 * (M0 + log2f(s_rows[r]));
        lsum += lse - 1000.0f * pos[r & (B_ROWS - 1)];
    }
    float psum = 0.f;
    for (int r = t; r < B_ROWS; r += 256) psum += pos[r];
    #pragma unroll
    for (int m = 1; m < 64; m <<= 1) {
        lsum += __shfl_xor(lsum, m);
        psum += __shfl_xor(psum, m);
    }
    __shared__ float red[2][4];
    const int w = t >> 6, l = t & 63;
    if (l == 0) { red[0][w] = lsum; red[1][w] = psum; }
    __syncthreads();
    if (t == 0) {
        const float L = red[0][0] + red[0][1] + red[0][2] + red[0][3];
        const float P = red[1][0] + red[1][1] + red[1][2] + red[1][3];
        out[0] = L / (float)TWO_B;
        out[1] = 2.0f * P;
    }
}

extern "C" void kernel_launch(void* const* d_in, const int* in_sizes, int n_in,
                              void* d_out, int out_size, void* d_ws, size_t ws_size,
                              hipStream_t stream) {
    const float* p1 = (const float*)d_in[0];
    const float* p2 = (const float*)d_in[1];
    float* out = (float*)d_out;
    char* ws = (char*)d_ws;

    __hip_bfloat16* reps = (__hip_bfloat16*)ws;                              // 4 MiB
    float* pos    = (float*)(ws + (size_t)TWO_B * D_DIM * 2);                // 16 KiB
    float* s_rows = (float*)(ws + (size_t)TWO_B * D_DIM * 2 + B_ROWS * 4);   // 32 KiB

    (void)hipMemsetAsync(s_rows, 0, TWO_B * sizeof(float), stream);
    k_prep<<<B_ROWS, 256, 0, stream>>>(p1, p2, reps, pos);
    dim3 g2(TWO_B / 128, TWO_B / CCHUNK);
    k_simlse<<<g2, 256, 0, stream>>>(reps, s_rows);
    k_final<<<1, 256, 0, stream>>>(s_rows, pos, out);
}

// Round 8
// 62.194 us; speedup vs baseline: 1.2229x; 1.2229x over previous
//
#include <hip/hip_runtime.h>
#include <hip/hip_bf16.h>

#define B_ROWS 4096
#define D_DIM  256
#define TWO_B  8192
// reps row stride in bytes = 256 * 2 = 512

typedef float f32x4  __attribute__((ext_vector_type(4)));
typedef short bf16x8 __attribute__((ext_vector_type(8)));

#define CCHUNK      1024
#define TPS         4               // 16-col tiles per LDS stage
#define STAGE_BYTES (TPS * 8192)    // 32 KiB per buffer
#define NSTAGES     (CCHUNK / (TPS * 16))

#define SC2 1442.6951f   // 1000 * log2(e)
#define M0  1442.6951f   // anchor: logit2 of sim == 1 (the diagonal)

__device__ __forceinline__ void async_copy16(void* lds_dst, const void* gsrc) {
    __builtin_amdgcn_global_load_lds(
        (__attribute__((address_space(1))) void*)(gsrc),
        (__attribute__((address_space(3))) void*)(lds_dst), 16, 0, 0);
}

// ---------------- kernel 1: normalize rows, compute positives, emit bf16 reps
// also zeroes s_rows (folded memset: block r zeroes rows r and B_ROWS+r)
__global__ __launch_bounds__(256) void k_prep(const float* __restrict__ p1,
                                              const float* __restrict__ p2,
                                              __hip_bfloat16* __restrict__ reps,
                                              float* __restrict__ pos,
                                              float* __restrict__ s_rows) {
    const int r = blockIdx.x;
    const int t = threadIdx.x;
    if (t < 2) s_rows[r + t * B_ROWS] = 0.f;
    float e1 = p1[r * D_DIM + t];
    float e2 = p2[r * D_DIM + t];
    float s11 = e1 * e1, s22 = e2 * e2, s12 = e1 * e2;
    #pragma unroll
    for (int m = 1; m < 64; m <<= 1) {
        s11 += __shfl_xor(s11, m);
        s22 += __shfl_xor(s22, m);
        s12 += __shfl_xor(s12, m);
    }
    __shared__ float red[3][4];
    const int w = t >> 6, l = t & 63;
    if (l == 0) { red[0][w] = s11; red[1][w] = s22; red[2][w] = s12; }
    __syncthreads();
    s11 = red[0][0] + red[0][1] + red[0][2] + red[0][3];
    s22 = red[1][0] + red[1][1] + red[1][2] + red[1][3];
    s12 = red[2][0] + red[2][1] + red[2][2] + red[2][3];
    const float n1 = fmaxf(sqrtf(s11), 1e-12f);
    const float n2 = fmaxf(sqrtf(s22), 1e-12f);
    reps[r * D_DIM + t]            = __float2bfloat16(e1 / n1);
    reps[(B_ROWS + r) * D_DIM + t] = __float2bfloat16(e2 / n2);
    if (t == 0) pos[r] = s12 / (n1 * n2);
}

// ---------------- kernel 2: fused reps·repsT -> row-wise sum of 2^(1443*sim - M0)
// WG: 256 thr (4 waves). Each wave: 32 rows (2 M-tiles). WG: 128 rows x CCHUNK cols.
// Double-buffered LDS staging: issue stage t+1's global_load_lds BEFORE computing
// stage t; one __syncthreads (vmcnt0+barrier) per stage. (T3 minimum 2-phase)
__global__ __launch_bounds__(256) void k_simlse(const __hip_bfloat16* __restrict__ reps,
                                                float* __restrict__ s_rows) {
    __shared__ char lds[2][STAGE_BYTES];
    const int t   = threadIdx.x;
    const int w   = t >> 6;
    const int l   = t & 63;
    const int c16 = l & 15;
    const int g   = l >> 4;     // 0..3

    const int row_base = blockIdx.x * 128 + w * 32;
    const int col_base = blockIdx.y * CCHUNK;
    const char* repsB = (const char*)reps;

    // A fragments in registers: 2 M-tiles x 8 k-steps, 16B per lane each
    bf16x8 afrag[2][8];
    #pragma unroll
    for (int mt = 0; mt < 2; ++mt) {
        const int arow = row_base + mt * 16 + c16;
        #pragma unroll
        for (int kk = 0; kk < 8; ++kk)
            afrag[mt][kk] = *(const bf16x8*)(repsB + arow * 512 + kk * 64 + g * 16);
    }

    float s[8];
    #pragma unroll
    for (int i = 0; i < 8; ++i) s[i] = 0.f;

    // stage TPS*16 cols x 256 k (bf16) into LDS buffer in fragment order:
    // lds[tt*8192 + kk*1024 + g*256 + c*16] = reps[cstage+tt*16+c][k = kk*32+g*8 .. +8]
    auto stage = [&](char* buf, int cstage) {
        #pragma unroll
        for (int i = 0; i < 8; ++i) {
            const int a  = i * 4096 + w * 1024 + l * 16;
            const int tt = a >> 13;
            const int rr = a & 8191;
            const int kk = rr >> 10;
            const int gg = (rr >> 8) & 3;
            const int cc = (rr >> 4) & 15;
            const int col = cstage + tt * 16 + cc;
            async_copy16(buf + i * 4096 + w * 1024,            // wave-uniform base; HW adds lane*16
                         repsB + col * 512 + kk * 64 + gg * 16);
        }
    };

    auto compute = [&](const char* buf) {
        #pragma unroll
        for (int tt = 0; tt < TPS; ++tt) {
            f32x4 acc0 = {0.f, 0.f, 0.f, 0.f};
            f32x4 acc1 = {0.f, 0.f, 0.f, 0.f};
            #pragma unroll
            for (int kk = 0; kk < 8; ++kk) {
                const bf16x8 b = *(const bf16x8*)(buf + tt * 8192 + kk * 1024 + l * 16);
                acc0 = __builtin_amdgcn_mfma_f32_16x16x32_bf16(afrag[0][kk], b, acc0, 0, 0, 0);
                acc1 = __builtin_amdgcn_mfma_f32_16x16x32_bf16(afrag[1][kk], b, acc1, 0, 0, 0);
            }
            // D layout: row = g*4 + reg, col = c16  (verified m89/m91)
            const float tmax =
                fmaxf(fmaxf(fmaxf(acc0[0], acc0[1]), fmaxf(acc0[2], acc0[3])),
                      fmaxf(fmaxf(acc1[0], acc1[1]), fmaxf(acc1[2], acc1[3])));
            // only tiles containing a diagonal element matter; dropped terms < 2^-144
            if (__any(tmax > 0.90f)) {
                #pragma unroll
                for (int r = 0; r < 4; ++r) s[r]     += exp2f(acc0[r] * SC2 - M0);
                #pragma unroll
                for (int r = 0; r < 4; ++r) s[4 + r] += exp2f(acc1[r] * SC2 - M0);
            }
        }
    };

    // prologue: fill buffer 0
    stage(lds[0], col_base);
    __syncthreads();                 // vmcnt(0) drain + barrier

    int cur = 0;
    for (int st = 0; st < NSTAGES; ++st) {
        if (st + 1 < NSTAGES)
            stage(lds[cur ^ 1], col_base + (st + 1) * (TPS * 16));  // prefetch next
        compute(lds[cur]);                                           // MFMA on current
        __syncthreads();             // prefetch landed + all waves done reading cur
        cur ^= 1;
    }

    // reduce s over the 16 lanes (cols) of each lane-group, then one atomic per row
    #pragma unroll
    for (int i = 0; i < 8; ++i) {
        #pragma unroll
        for (int m = 1; m < 16; m <<= 1) s[i] += __shfl_xor(s[i], m);
    }
    if (c16 == 0) {
        #pragma unroll
        for (int mt = 0; mt < 2; ++mt)
            #pragma unroll
            for (int r = 0; r < 4; ++r)
                atomicAdd(&s_rows[row_base + mt * 16 + g * 4 + r], s[mt * 4 + r]);
    }
}

// ---------------- kernel 3: finalize loss and sum(positives)
__global__ __launch_bounds__(256) void k_final(const float* __restrict__ s_rows,
                                               const float* __restrict__ pos,
                                               float* __restrict__ out) {
    const float LN2 = 0.69314718f;
    const int t = threadIdx.x;
    float lsum = 0.f;
    for (int r = t; r < TWO_B; r += 256) {
        const float lse = LN2 * (M0 + log2f(s_rows[r]));
        lsum += lse - 1000.0f * pos[r & (B_ROWS - 1)];
    }
    float psum = 0.f;
    for (int r = t; r < B_ROWS; r += 256) psum += pos[r];
    #pragma unroll
    for (int m = 1; m < 64; m <<= 1) {
        lsum += __shfl_xor(lsum, m);
        psum += __shfl_xor(psum, m);
    }
    __shared__ float red[2][4];
    const int w = t >> 6, l = t & 63;
    if (l == 0) { red[0][w] = lsum; red[1][w] = psum; }
    __syncthreads();
    if (t == 0) {
        const float L = red[0][0] + red[0][1] + red[0][2] + red[0][3];
        const float P = red[1][0] + red[1][1] + red[1][2] + red[1][3];
        out[0] = L / (float)TWO_B;
        out[1] = 2.0f * P;
    }
}

extern "C" void kernel_launch(void* const* d_in, const int* in_sizes, int n_in,
                              void* d_out, int out_size, void* d_ws, size_t ws_size,
                              hipStream_t stream) {
    const float* p1 = (const float*)d_in[0];
    const float* p2 = (const float*)d_in[1];
    float* out = (float*)d_out;
    char* ws = (char*)d_ws;

    __hip_bfloat16* reps = (__hip_bfloat16*)ws;                              // 4 MiB
    float* pos    = (float*)(ws + (size_t)TWO_B * D_DIM * 2);                // 16 KiB
    float* s_rows = (float*)(ws + (size_t)TWO_B * D_DIM * 2 + B_ROWS * 4);   // 32 KiB

    k_prep<<<B_ROWS, 256, 0, stream>>>(p1, p2, reps, pos, s_rows);
    dim3 g2(TWO_B / 128, TWO_B / CCHUNK);
    k_simlse<<<g2, 256, 0, stream>>>(reps, s_rows);
    k_final<<<1, 256, 0, stream>>>(s_rows, pos, out);
}

// Round 11
// 61.835 us; speedup vs baseline: 1.2300x; 1.0058x over previous
//
#include <hip/hip_runtime.h>
#include <hip/hip_bf16.h>

#define B_ROWS 4096
#define D_DIM  256
#define TWO_B  8192
// reps row stride in bytes = 256 * 2 = 512

typedef float f32x4  __attribute__((ext_vector_type(4)));
typedef short bf16x8 __attribute__((ext_vector_type(8)));

#define CCHUNK      512
#define TPS         4               // 16-col tiles per LDS stage
#define STAGE_BYTES (TPS * 8192)    // 32 KiB per buffer
#define NSTAGES     (CCHUNK / (TPS * 16))
#define MT          4               // M-tiles (16 rows each) per wave = 64 rows

#define SC2 1442.6951f   // 1000 * log2(e)
#define M0  1442.6951f   // anchor: logit2 of sim == 1 (the diagonal)

__device__ __forceinline__ void async_copy16(void* lds_dst, const void* gsrc) {
    __builtin_amdgcn_global_load_lds(
        (__attribute__((address_space(1))) void*)(gsrc),
        (__attribute__((address_space(3))) void*)(lds_dst), 16, 0, 0);
}

// ---------------- kernel 1: normalize rows, compute positives, emit bf16 reps
// also zeroes s_rows (folded memset: block r zeroes rows r and B_ROWS+r)
__global__ __launch_bounds__(256) void k_prep(const float* __restrict__ p1,
                                              const float* __restrict__ p2,
                                              __hip_bfloat16* __restrict__ reps,
                                              float* __restrict__ pos,
                                              float* __restrict__ s_rows) {
    const int r = blockIdx.x;
    const int t = threadIdx.x;
    if (t < 2) s_rows[r + t * B_ROWS] = 0.f;
    float e1 = p1[r * D_DIM + t];
    float e2 = p2[r * D_DIM + t];
    float s11 = e1 * e1, s22 = e2 * e2, s12 = e1 * e2;
    #pragma unroll
    for (int m = 1; m < 64; m <<= 1) {
        s11 += __shfl_xor(s11, m);
        s22 += __shfl_xor(s22, m);
        s12 += __shfl_xor(s12, m);
    }
    __shared__ float red[3][4];
    const int w = t >> 6, l = t & 63;
    if (l == 0) { red[0][w] = s11; red[1][w] = s22; red[2][w] = s12; }
    __syncthreads();
    s11 = red[0][0] + red[0][1] + red[0][2] + red[0][3];
    s22 = red[1][0] + red[1][1] + red[1][2] + red[1][3];
    s12 = red[2][0] + red[2][1] + red[2][2] + red[2][3];
    const float n1 = fmaxf(sqrtf(s11), 1e-12f);
    const float n2 = fmaxf(sqrtf(s22), 1e-12f);
    reps[r * D_DIM + t]            = __float2bfloat16(e1 / n1);
    reps[(B_ROWS + r) * D_DIM + t] = __float2bfloat16(e2 / n2);
    if (t == 0) pos[r] = s12 / (n1 * n2);
}

// ---------------- kernel 2: fused reps·repsT -> row-wise sum of 2^(1443*sim - M0)
// WG: 256 thr (4 waves). Each wave: 64 rows (4 M-tiles) -> 1 ds_read feeds 4 MFMAs.
// WG covers 256 rows x CCHUNK cols. Double-buffered LDS staging (T3 2-phase).
__global__ __launch_bounds__(256, 2) void k_simlse(const __hip_bfloat16* __restrict__ reps,
                                                   float* __restrict__ s_rows) {
    __shared__ char lds[2][STAGE_BYTES];
    const int t   = threadIdx.x;
    const int w   = t >> 6;
    const int l   = t & 63;
    const int c16 = l & 15;
    const int g   = l >> 4;     // 0..3

    const int row_base = blockIdx.x * 256 + w * 64;
    const int col_base = blockIdx.y * CCHUNK;
    const char* repsB = (const char*)reps;

    // A fragments in registers: 4 M-tiles x 8 k-steps, 16B per lane each (128 VGPR)
    bf16x8 afrag[MT][8];
    #pragma unroll
    for (int mt = 0; mt < MT; ++mt) {
        const int arow = row_base + mt * 16 + c16;
        #pragma unroll
        for (int kk = 0; kk < 8; ++kk)
            afrag[mt][kk] = *(const bf16x8*)(repsB + arow * 512 + kk * 64 + g * 16);
    }

    float s[4 * MT];
    #pragma unroll
    for (int i = 0; i < 4 * MT; ++i) s[i] = 0.f;

    // stage TPS*16 cols x 256 k (bf16) into LDS buffer in fragment order:
    // buf[tt*8192 + kk*1024 + g*256 + c*16] = reps[cstage+tt*16+c][k = kk*32+g*8 .. +8]
    auto stage = [&](char* buf, int cstage) {
        #pragma unroll
        for (int i = 0; i < 8; ++i) {
            const int a  = i * 4096 + w * 1024 + l * 16;
            const int tt = a >> 13;
            const int rr = a & 8191;
            const int kk = rr >> 10;
            const int gg = (rr >> 8) & 3;
            const int cc = (rr >> 4) & 15;
            const int col = cstage + tt * 16 + cc;
            async_copy16(buf + i * 4096 + w * 1024,            // wave-uniform base; HW adds lane*16
                         repsB + col * 512 + kk * 64 + gg * 16);
        }
    };

    auto compute = [&](const char* buf) {
        #pragma unroll
        for (int tt = 0; tt < TPS; ++tt) {
            f32x4 acc[MT];
            #pragma unroll
            for (int mt = 0; mt < MT; ++mt) acc[mt] = f32x4{0.f, 0.f, 0.f, 0.f};
            #pragma unroll
            for (int kk = 0; kk < 8; ++kk) {
                const bf16x8 b = *(const bf16x8*)(buf + tt * 8192 + kk * 1024 + l * 16);
                #pragma unroll
                for (int mt = 0; mt < MT; ++mt)
                    acc[mt] = __builtin_amdgcn_mfma_f32_16x16x32_bf16(afrag[mt][kk], b, acc[mt], 0, 0, 0);
            }
            // D layout: row = g*4 + reg (within M-tile), col = c16
            float tmax = acc[0][0];
            #pragma unroll
            for (int mt = 0; mt < MT; ++mt)
                #pragma unroll
                for (int r = 0; r < 4; ++r) tmax = fmaxf(tmax, acc[mt][r]);
            // only tiles containing a diagonal element matter; dropped terms < 2^-144
            if (__any(tmax > 0.90f)) {
                #pragma unroll
                for (int mt = 0; mt < MT; ++mt)
                    #pragma unroll
                    for (int r = 0; r < 4; ++r)
                        s[mt * 4 + r] += exp2f(acc[mt][r] * SC2 - M0);
            }
        }
    };

    // prologue: fill buffer 0
    stage(lds[0], col_base);
    __syncthreads();                 // vmcnt(0) drain + barrier

    int cur = 0;
    for (int st = 0; st < NSTAGES; ++st) {
        if (st + 1 < NSTAGES)
            stage(lds[cur ^ 1], col_base + (st + 1) * (TPS * 16));  // prefetch next
        compute(lds[cur]);                                           // MFMA on current
        __syncthreads();             // prefetch landed + all waves done reading cur
        cur ^= 1;
    }

    // reduce s over the 16 lanes (cols) of each lane-group, then one atomic per row
    #pragma unroll
    for (int i = 0; i < 4 * MT; ++i) {
        #pragma unroll
        for (int m = 1; m < 16; m <<= 1) s[i] += __shfl_xor(s[i], m);
    }
    if (c16 == 0) {
        #pragma unroll
        for (int mt = 0; mt < MT; ++mt)
            #pragma unroll
            for (int r = 0; r < 4; ++r)
                atomicAdd(&s_rows[row_base + mt * 16 + g * 4 + r], s[mt * 4 + r]);
    }
}

// ---------------- kernel 3: finalize loss and sum(positives)
__global__ __launch_bounds__(256) void k_final(const float* __restrict__ s_rows,
                                               const float* __restrict__ pos,
                                               float* __restrict__ out) {
    const float LN2 = 0.69314718f;
    const int t = threadIdx.x;
    float lsum = 0.f;
    for (int r = t; r < TWO_B; r += 256) {
        const float lse = LN2 * (M0 + log2f(s_rows[r]));
        lsum += lse - 1000.0f * pos[r & (B_ROWS - 1)];
    }
    float psum = 0.f;
    for (int r = t; r < B_ROWS; r += 256) psum += pos[r];
    #pragma unroll
    for (int m = 1; m < 64; m <<= 1) {
        lsum += __shfl_xor(lsum, m);
        psum += __shfl_xor(psum, m);
    }
    __shared__ float red[2][4];
    const int w = t >> 6, l = t & 63;
    if (l == 0) { red[0][w] = lsum; red[1][w] = psum; }
    __syncthreads();
    if (t == 0) {
        const float L = red[0][0] + red[0][1] + red[0][2] + red[0][3];
        const float P = red[1][0] + red[1][1] + red[1][2] + red[1][3];
        out[0] = L / (float)TWO_B;
        out[1] = 2.0f * P;
    }
}

extern "C" void kernel_launch(void* const* d_in, const int* in_sizes, int n_in,
                              void* d_out, int out_size, void* d_ws, size_t ws_size,
                              hipStream_t stream) {
    const float* p1 = (const float*)d_in[0];
    const float* p2 = (const float*)d_in[1];
    float* out = (float*)d_out;
    char* ws = (char*)d_ws;

    __hip_bfloat16* reps = (__hip_bfloat16*)ws;                              // 4 MiB
    float* pos    = (float*)(ws + (size_t)TWO_B * D_DIM * 2);                // 16 KiB
    float* s_rows = (float*)(ws + (size_t)TWO_B * D_DIM * 2 + B_ROWS * 4);   // 32 KiB

    k_prep<<<B_ROWS, 256, 0, stream>>>(p1, p2, reps, pos, s_rows);
    dim3 g2(TWO_B / 256, TWO_B / CCHUNK);
    k_simlse<<<g2, 256, 0, stream>>>(reps, s_rows);
    k_final<<<1, 256, 0, stream>>>(s_rows, pos, out);
}

// Round 13
// 59.980 us; speedup vs baseline: 1.2680x; 1.0309x over previous
//
#include <hip/hip_runtime.h>
#include <hip/hip_bf16.h>

#define B_ROWS 4096
#define D_DIM  256
#define TWO_B  8192
// reps row stride in bytes = 256 * 2 = 512

typedef float f32x4  __attribute__((ext_vector_type(4)));
typedef short bf16x8 __attribute__((ext_vector_type(8)));

#define CCHUNK      512
#define TPS         4               // 16-col tiles per LDS stage
#define STAGE_BYTES (TPS * 8192)    // 32 KiB per buffer
#define NSTAGES     (CCHUNK / (TPS * 16))
#define MT          4               // M-tiles (16 rows each) per wave = 64 rows
#define GY          (TWO_B / CCHUNK)  // 16 column chunks

#define SC2 1442.6951f   // 1000 * log2(e)
#define M0  1442.6951f   // anchor: logit2 of sim == 1 (the diagonal)

__device__ __forceinline__ void async_copy16(void* lds_dst, const void* gsrc) {
    __builtin_amdgcn_global_load_lds(
        (__attribute__((address_space(1))) void*)(gsrc),
        (__attribute__((address_space(3))) void*)(lds_dst), 16, 0, 0);
}

// ---------------- kernel 1: normalize rows, compute positives, emit bf16 reps
__global__ __launch_bounds__(256) void k_prep(const float* __restrict__ p1,
                                              const float* __restrict__ p2,
                                              __hip_bfloat16* __restrict__ reps,
                                              float* __restrict__ pos) {
    const int r = blockIdx.x;
    const int t = threadIdx.x;
    float e1 = p1[r * D_DIM + t];
    float e2 = p2[r * D_DIM + t];
    float s11 = e1 * e1, s22 = e2 * e2, s12 = e1 * e2;
    #pragma unroll
    for (int m = 1; m < 64; m <<= 1) {
        s11 += __shfl_xor(s11, m);
        s22 += __shfl_xor(s22, m);
        s12 += __shfl_xor(s12, m);
    }
    __shared__ float red[3][4];
    const int w = t >> 6, l = t & 63;
    if (l == 0) { red[0][w] = s11; red[1][w] = s22; red[2][w] = s12; }
    __syncthreads();
    s11 = red[0][0] + red[0][1] + red[0][2] + red[0][3];
    s22 = red[1][0] + red[1][1] + red[1][2] + red[1][3];
    s12 = red[2][0] + red[2][1] + red[2][2] + red[2][3];
    const float n1 = fmaxf(sqrtf(s11), 1e-12f);
    const float n2 = fmaxf(sqrtf(s22), 1e-12f);
    reps[r * D_DIM + t]            = __float2bfloat16(e1 / n1);
    reps[(B_ROWS + r) * D_DIM + t] = __float2bfloat16(e2 / n2);
    if (t == 0) pos[r] = s12 / (n1 * n2);
}

// ---------------- kernel 2: fused reps·repsT -> row-wise sum of 2^(1443*sim - M0)
// WG: 256 thr (4 waves). Each wave: 64 rows (4 M-tiles) -> 1 ds_read feeds 4 MFMAs.
// WG covers 256 rows x CCHUNK cols. Double-buffered LDS staging (T3 2-phase).
// Epilogue: NO atomics — per-chunk partials to s_part[row][gy], each cell written once.
__global__ __launch_bounds__(256, 2) void k_simlse(const __hip_bfloat16* __restrict__ reps,
                                                   float* __restrict__ s_part) {
    __shared__ char lds[2][STAGE_BYTES];
    const int t   = threadIdx.x;
    const int w   = t >> 6;
    const int l   = t & 63;
    const int c16 = l & 15;
    const int g   = l >> 4;     // 0..3

    const int row_base = blockIdx.x * 256 + w * 64;
    const int gy       = blockIdx.y;
    const int col_base = gy * CCHUNK;
    const char* repsB = (const char*)reps;

    // A fragments in registers: 4 M-tiles x 8 k-steps, 16B per lane each (128 VGPR)
    bf16x8 afrag[MT][8];
    #pragma unroll
    for (int mt = 0; mt < MT; ++mt) {
        const int arow = row_base + mt * 16 + c16;
        #pragma unroll
        for (int kk = 0; kk < 8; ++kk)
            afrag[mt][kk] = *(const bf16x8*)(repsB + arow * 512 + kk * 64 + g * 16);
    }

    float s[4 * MT];
    #pragma unroll
    for (int i = 0; i < 4 * MT; ++i) s[i] = 0.f;

    // stage TPS*16 cols x 256 k (bf16) into LDS buffer in fragment order:
    // buf[tt*8192 + kk*1024 + g*256 + c*16] = reps[cstage+tt*16+c][k = kk*32+g*8 .. +8]
    auto stage = [&](char* buf, int cstage) {
        #pragma unroll
        for (int i = 0; i < 8; ++i) {
            const int a  = i * 4096 + w * 1024 + l * 16;
            const int tt = a >> 13;
            const int rr = a & 8191;
            const int kk = rr >> 10;
            const int gg = (rr >> 8) & 3;
            const int cc = (rr >> 4) & 15;
            const int col = cstage + tt * 16 + cc;
            async_copy16(buf + i * 4096 + w * 1024,            // wave-uniform base; HW adds lane*16
                         repsB + col * 512 + kk * 64 + gg * 16);
        }
    };

    auto compute = [&](const char* buf) {
        #pragma unroll
        for (int tt = 0; tt < TPS; ++tt) {
            f32x4 acc[MT];
            #pragma unroll
            for (int mt = 0; mt < MT; ++mt) acc[mt] = f32x4{0.f, 0.f, 0.f, 0.f};
            #pragma unroll
            for (int kk = 0; kk < 8; ++kk) {
                const bf16x8 b = *(const bf16x8*)(buf + tt * 8192 + kk * 1024 + l * 16);
                #pragma unroll
                for (int mt = 0; mt < MT; ++mt)
                    acc[mt] = __builtin_amdgcn_mfma_f32_16x16x32_bf16(afrag[mt][kk], b, acc[mt], 0, 0, 0);
            }
            // D layout: row = g*4 + reg (within M-tile), col = c16
            float tmax = acc[0][0];
            #pragma unroll
            for (int mt = 0; mt < MT; ++mt)
                #pragma unroll
                for (int r = 0; r < 4; ++r) tmax = fmaxf(tmax, acc[mt][r]);
            // only tiles containing a diagonal element matter; dropped terms < 2^-144
            if (__any(tmax > 0.90f)) {
                #pragma unroll
                for (int mt = 0; mt < MT; ++mt)
                    #pragma unroll
                    for (int r = 0; r < 4; ++r)
                        s[mt * 4 + r] += exp2f(acc[mt][r] * SC2 - M0);
            }
        }
    };

    // prologue: fill buffer 0
    stage(lds[0], col_base);
    __syncthreads();                 // vmcnt(0) drain + barrier

    int cur = 0;
    for (int st = 0; st < NSTAGES; ++st) {
        if (st + 1 < NSTAGES)
            stage(lds[cur ^ 1], col_base + (st + 1) * (TPS * 16));  // prefetch next
        compute(lds[cur]);                                           // MFMA on current
        __syncthreads();             // prefetch landed + all waves done reading cur
        cur ^= 1;
    }

    // reduce s over the 16 lanes (cols) of each lane-group, then one plain store per row
    #pragma unroll
    for (int i = 0; i < 4 * MT; ++i) {
        #pragma unroll
        for (int m = 1; m < 16; m <<= 1) s[i] += __shfl_xor(s[i], m);
    }
    if (c16 == 0) {
        #pragma unroll
        for (int mt = 0; mt < MT; ++mt)
            #pragma unroll
            for (int r = 0; r < 4; ++r)
                s_part[(row_base + mt * 16 + g * 4 + r) * GY + gy] = s[mt * 4 + r];
    }
}

// ---------------- kernel 3: finalize loss and sum(positives). 1 WG x 1024 thr.
__global__ __launch_bounds__(1024) void k_final(const float* __restrict__ s_part,
                                                const float* __restrict__ pos,
                                                float* __restrict__ out) {
    const float LN2 = 0.69314718f;
    const int t = threadIdx.x;
    float lsum = 0.f;
    for (int r = t; r < TWO_B; r += 1024) {
        const f32x4* p4 = (const f32x4*)(s_part + r * GY);
        const f32x4 a = p4[0], b = p4[1], c = p4[2], d = p4[3];
        const float srow = ((a[0] + a[1]) + (a[2] + a[3])) + ((b[0] + b[1]) + (b[2] + b[3]))
                         + ((c[0] + c[1]) + (c[2] + c[3])) + ((d[0] + d[1]) + (d[2] + d[3]));
        lsum += LN2 * (M0 + log2f(srow)) - 1000.0f * pos[r & (B_ROWS - 1)];
    }
    float psum = 0.f;
    for (int r = t; r < B_ROWS; r += 1024) psum += pos[r];
    #pragma unroll
    for (int m = 1; m < 64; m <<= 1) {
        lsum += __shfl_xor(lsum, m);
        psum += __shfl_xor(psum, m);
    }
    __shared__ float red[2][16];
    const int w = t >> 6, l = t & 63;
    if (l == 0) { red[0][w] = lsum; red[1][w] = psum; }
    __syncthreads();
    if (t == 0) {
        float L = 0.f, P = 0.f;
        #pragma unroll
        for (int i = 0; i < 16; ++i) { L += red[0][i]; P += red[1][i]; }
        out[0] = L / (float)TWO_B;
        out[1] = 2.0f * P;
    }
}

extern "C" void kernel_launch(void* const* d_in, const int* in_sizes, int n_in,
                              void* d_out, int out_size, void* d_ws, size_t ws_size,
                              hipStream_t stream) {
    const float* p1 = (const float*)d_in[0];
    const float* p2 = (const float*)d_in[1];
    float* out = (float*)d_out;
    char* ws = (char*)d_ws;

    __hip_bfloat16* reps = (__hip_bfloat16*)ws;                              // 4 MiB
    float* pos    = (float*)(ws + (size_t)TWO_B * D_DIM * 2);                // 16 KiB
    float* s_part = (float*)(ws + (size_t)TWO_B * D_DIM * 2 + B_ROWS * 4);   // 8192*16 fp32 = 512 KiB

    k_prep<<<B_ROWS, 256, 0, stream>>>(p1, p2, reps, pos);
    dim3 g2(TWO_B / 256, GY);
    k_simlse<<<g2, 256, 0, stream>>>(reps, s_part);
    k_final<<<1, 1024, 0, stream>>>(s_part, pos, out);
}